// Round 1
// baseline (53.405 us; speedup 1.0000x reference)
//
#include <hip/hip_runtime.h>

// dEMD greedy multi-marginal EMD, D=4 rows, N=2048 bins.
//
// Closed-form reformulation of the sequential greedy loop:
//   Every greedy step subtracts minval from ALL row fronts, so the consumed
//   mass T is identical across rows at all times. Pointer of row i at mass T:
//       idx_i(T) = #{ j in [1..N] : S_i(j) <= T },  S_i = inclusive prefix sum
//   Loop terminates at Tend = min_i S_i(N) (first pointer reaches N).
//   obj = integral over [0,Tend] of (max_i idx_i - min_i idx_i) dT
//       = sum_{m=1..N} (Tend - A_m) - max(0, Tend - B_m)
//       = sum_{m=1..N} min(Tend, B_m) - A_m          // exact rewrite, inputs >= 0
//   with A_m = min_i S_i(m), B_m = max_i S_i(m)  (level-set decomposition).
//   (A_m <= Tend always: prefixes are nondecreasing, so min_i S_i(m) <= min_i S_i(N).)
//
// R3: single-wave, all-fp32, zero-LDS. Each lane owns a 32-column chunk of
// ALL FOUR rows in registers; the 4 row-scans run as independent dependent
// chains (4-way ILP); cross-row min/max is per-lane register math; final sum
// is one shuffle reduction. Walk body reduced to min(tend,b)-a with two
// independent accumulator chains.

constexpr int D        = 4;
constexpr int N        = 2048;
constexpr int PER_LANE = N / 64;    // 32 columns per lane

__global__ __launch_bounds__(64)
void demd_kernel(const float* __restrict__ x, float* __restrict__ out) {
    const int lane = threadIdx.x;

    // ---- load: 4 rows x 32 columns per lane (128 B per row per lane) ----
    float v[D][PER_LANE];
    #pragma unroll
    for (int r = 0; r < D; ++r) {
        const float4* src = (const float4*)(x + r * N + lane * PER_LANE);
        #pragma unroll
        for (int k = 0; k < PER_LANE / 4; ++k) {
            float4 f = src[k];
            v[r][4*k+0] = f.x; v[r][4*k+1] = f.y;
            v[r][4*k+2] = f.z; v[r][4*k+3] = f.w;
        }
    }

    // ---- lane totals per row (4 independent chains, ILP=4) ----
    float tot[D];
    #pragma unroll
    for (int r = 0; r < D; ++r) {
        float s = 0.0f;
        #pragma unroll
        for (int k = 0; k < PER_LANE; ++k) s += v[r][k];
        tot[r] = s;
    }

    // ---- wave-level inclusive scan of lane totals, 4 rows interleaved ----
    float scan[D];
    #pragma unroll
    for (int r = 0; r < D; ++r) scan[r] = tot[r];
    #pragma unroll
    for (int off = 1; off < 64; off <<= 1) {
        #pragma unroll
        for (int r = 0; r < D; ++r) {
            float up = __shfl_up(scan[r], off, 64);
            if (lane >= off) scan[r] += up;
        }
    }

    // ---- Tend = min over rows of full-row sum (lane 63's inclusive scan) --
    float tend = __shfl(scan[0], 63, 64);
    #pragma unroll
    for (int r = 1; r < D; ++r) tend = fminf(tend, __shfl(scan[r], 63, 64));

    // ---- walk the 32 columns: running prefixes, min/max across rows ----
    float run[D];
    #pragma unroll
    for (int r = 0; r < D; ++r) run[r] = scan[r] - tot[r];  // exclusive prefix

    float accB = 0.0f;   // sum of min(tend, B_m)
    float accA = 0.0f;   // sum of A_m
    #pragma unroll
    for (int k = 0; k < PER_LANE; ++k) {
        #pragma unroll
        for (int r = 0; r < D; ++r) run[r] += v[r][k];
        float a01 = fminf(run[0], run[1]), a23 = fminf(run[2], run[3]);
        float b01 = fmaxf(run[0], run[1]), b23 = fmaxf(run[2], run[3]);
        accA += fminf(a01, a23);
        accB += fminf(tend, fmaxf(b01, b23));
    }
    float acc = accB - accA;

    // ---- wave reduction of acc ----
    #pragma unroll
    for (int off = 32; off > 0; off >>= 1)
        acc += __shfl_down(acc, off, 64);
    if (lane == 0) out[0] = acc;
}

extern "C" void kernel_launch(void* const* d_in, const int* in_sizes, int n_in,
                              void* d_out, int out_size, void* d_ws, size_t ws_size,
                              hipStream_t stream) {
    (void)in_sizes; (void)n_in; (void)d_ws; (void)ws_size; (void)out_size;
    const float* x = (const float*)d_in[0];
    float* out = (float*)d_out;
    demd_kernel<<<1, 64, 0, stream>>>(x, out);
}